// Round 16
// baseline (127.316 us; speedup 1.0000x reference)
//
#include <hip/hip_runtime.h>

typedef __attribute__((ext_vector_type(8))) short short8;
typedef __attribute__((ext_vector_type(4))) float float4v;
typedef __attribute__((ext_vector_type(4))) unsigned int uint4v;
typedef __attribute__((ext_vector_type(4))) unsigned short ushort4v;

__device__ __forceinline__ float lrelu(float v) { return v >= 0.f ? v : 0.01f * v; }

__device__ __forceinline__ unsigned short f2bf(float x) {
    union { float f; unsigned u; } c; c.f = x;
    unsigned r = (c.u + 0x7FFFu + ((c.u >> 16) & 1u)) >> 16;
    return (unsigned short)r;
}
__device__ __forceinline__ float bf2f(unsigned short h) {
    union { unsigned u; float f; } c; c.u = ((unsigned)h) << 16;
    return c.f;
}

// async global->LDS, 16B per lane. LDS dest must be wave-uniform base
// (HW adds lane*16); global src is per-lane (pre-swizzled).
__device__ __forceinline__ void gload16(const unsigned short* g, unsigned short* l) {
    __builtin_amdgcn_global_load_lds(
        (const __attribute__((address_space(1))) unsigned int*)g,
        (__attribute__((address_space(3))) unsigned int*)l, 16, 0, 0);
}

// ===========================================================================
// Shared MFMA core (K-range for split-K): C[128x128] += A.B^T over
// K in [kBeg,kEnd), split-bf16 (hh+hl+lh ~ fp32). 256 threads, 4 waves 2x2.
// LDS: 4 tiles [128][64]. gload_lds direct staging, both-sides XOR swizzle.
// ===========================================================================
__device__ __forceinline__ void mfma_core(
    const unsigned short* __restrict__ Ah, const unsigned short* __restrict__ Al, int lda,
    const unsigned short* __restrict__ Bh, const unsigned short* __restrict__ Bl, int ldb,
    unsigned short* lds, float4v acc[4][4], int kBeg, int kEnd) {
    const int tid = threadIdx.x;
    const int lane = tid & 63, wave = tid >> 6;
    const int wm = wave >> 1, wn = wave & 1;
    const int l15 = lane & 15, lhi = lane >> 4;
    unsigned short* LAh = lds;
    unsigned short* LAl = lds + 8192;
    unsigned short* LBh = lds + 16384;
    unsigned short* LBl = lds + 24576;

    for (int k0 = kBeg; k0 < kEnd; k0 += 64) {
#pragma unroll
        for (int tile = 0; tile < 4; ++tile) {
            const unsigned short* s = (tile == 0) ? Ah : (tile == 1) ? Al : (tile == 2) ? Bh : Bl;
            int ld = (tile < 2) ? lda : ldb;
            unsigned short* dbase = lds + tile * 8192;
#pragma unroll
            for (int it = 0; it < 4; ++it) {
                int idx = it * 256 + tid;
                int row = idx >> 3, ch = idx & 7;
                gload16(&s[row * ld + k0 + ((ch ^ (row & 7)) << 3)],
                        dbase + ((it * 256 + wave * 64) << 3));
            }
        }
        __syncthreads();
#pragma unroll
        for (int ks = 0; ks < 2; ++ks) {
            short8 ah[4], al[4], bh[4], bl[4];
#pragma unroll
            for (int m = 0; m < 4; ++m) {
                int r = wm * 64 + m * 16 + l15;
                int off = r * 64 + (((ks * 4 + lhi) ^ (r & 7)) * 8);
                ah[m] = *(const short8*)&LAh[off];
                al[m] = *(const short8*)&LAl[off];
            }
#pragma unroll
            for (int n = 0; n < 4; ++n) {
                int r = wn * 64 + n * 16 + l15;
                int off = r * 64 + (((ks * 4 + lhi) ^ (r & 7)) * 8);
                bh[n] = *(const short8*)&LBh[off];
                bl[n] = *(const short8*)&LBl[off];
            }
#pragma unroll
            for (int m = 0; m < 4; ++m)
#pragma unroll
                for (int n = 0; n < 4; ++n) {
                    acc[m][n] = __builtin_amdgcn_mfma_f32_16x16x32_bf16(ah[m], bh[n], acc[m][n], 0, 0, 0);
                    acc[m][n] = __builtin_amdgcn_mfma_f32_16x16x32_bf16(ah[m], bl[n], acc[m][n], 0, 0, 0);
                    acc[m][n] = __builtin_amdgcn_mfma_f32_16x16x32_bf16(al[m], bh[n], acc[m][n], 0, 0, 0);
                }
        }
        __syncthreads();
    }
}

// ---------------------------------------------------------------------------
// Fused ALL splits (r16): flat grid 4608, block (32,8).
//   bz < 1536: weight splits, z = bz/256 (0-2 transpose theta/phi/g;
//              3-5 straight W_w/p1/p2), 16x16 tile grid.
//   bz >= 1536: input transpose+split (Xh/Xl/Xf), 16x4 tile grid x 48.
// ---------------------------------------------------------------------------
__global__ __launch_bounds__(256) void k_split_all(
    const float* __restrict__ tw, const float* __restrict__ fw,
    const float* __restrict__ gw, const float* __restrict__ ww,
    const float* __restrict__ p1w, const float* __restrict__ p2w,
    const float* __restrict__ o1, const float* __restrict__ o2,
    const float* __restrict__ o3,
    unsigned short* __restrict__ TtH, unsigned short* __restrict__ TtL,
    unsigned short* __restrict__ PtH, unsigned short* __restrict__ PtL,
    unsigned short* __restrict__ GtH, unsigned short* __restrict__ GtL,
    unsigned short* __restrict__ WwH, unsigned short* __restrict__ WwL,
    unsigned short* __restrict__ p1h, unsigned short* __restrict__ p1l,
    unsigned short* __restrict__ p2h, unsigned short* __restrict__ p2l,
    unsigned short* __restrict__ Xh, unsigned short* __restrict__ Xl,
    float* __restrict__ Xf) {
    int bz = blockIdx.x;
    int tx = threadIdx.x, ty = threadIdx.y;
    __shared__ float tile[32][33];
    if (bz < 1536) {
        int z = bz >> 8, rem = bz & 255;
        int by = rem >> 4, bx = rem & 15;
        int i0 = bx * 32, k0 = by * 32;
        if (z < 3) {
            const float* src = (z == 0) ? tw : (z == 1) ? fw : gw;
            unsigned short* dh = (z == 0) ? TtH : (z == 1) ? PtH : GtH;
            unsigned short* dl = (z == 0) ? TtL : (z == 1) ? PtL : GtL;
#pragma unroll
            for (int i = 0; i < 4; ++i)
                tile[ty + i * 8][tx] = src[(k0 + ty + i * 8) * 512 + i0 + tx];
            __syncthreads();
#pragma unroll
            for (int i = 0; i < 4; ++i) {
                int row = i0 + ty + i * 8;
                float v = tile[tx][ty + i * 8];
                unsigned short h = f2bf(v), l = f2bf(v - bf2f(h));
                int idx = row * 512 + k0 + tx;
                dh[idx] = h;
                dl[idx] = l;
            }
        } else {
            const float* src = (z == 3) ? ww : (z == 4) ? p1w : p2w;
            unsigned short* dh = (z == 3) ? WwH : (z == 4) ? p1h : p2h;
            unsigned short* dl = (z == 3) ? WwL : (z == 4) ? p1l : p2l;
#pragma unroll
            for (int i = 0; i < 4; ++i) {
                int r = k0 + ty + i * 8;
                int idx = r * 512 + i0 + tx;
                float v = src[idx];
                unsigned short h = f2bf(v), l = f2bf(v - bf2f(h));
                dh[idx] = h;
                dl[idx] = l;
            }
        }
    } else {
        int r = bz - 1536;
        int z = r >> 6, rem = r & 63;
        int by = rem >> 4, bx = rem & 15;
        int b = z / 3, k = z - b * 3;
        const float* In = (k == 0) ? o1 : ((k == 1) ? o2 : o3);
        int c0 = bx * 32, t0 = by * 32;
#pragma unroll
        for (int i = 0; i < 4; ++i)
            tile[ty + i * 8][tx] = In[(b * 512 + c0 + ty + i * 8) * 128 + t0 + tx];
        __syncthreads();
#pragma unroll
        for (int i = 0; i < 4; ++i) {
            int t = t0 + ty + i * 8;
            float v = tile[tx][ty + i * 8];
            unsigned short h = f2bf(v), l = f2bf(v - bf2f(h));
            int idx = ((b * 128 + t) * 3 + k) * 512 + c0 + tx;
            Xh[idx] = h;
            Xl[idx] = l;
            Xf[idx] = v;
        }
    }
}

// ---------------------------------------------------------------------------
// Weight GEMMs, split-K=4: grid (4,4,8): z = wg*4 + kslice.
// ---------------------------------------------------------------------------
__global__ __launch_bounds__(256) void k_wgemm_sk(
    const unsigned short* __restrict__ WwH, const unsigned short* __restrict__ WwL,
    const unsigned short* __restrict__ GtH, const unsigned short* __restrict__ GtL,
    const unsigned short* __restrict__ TtH, const unsigned short* __restrict__ TtL,
    const unsigned short* __restrict__ PtH, const unsigned short* __restrict__ PtL,
    float* __restrict__ Pw) {
    __shared__ unsigned short lds[32768];
    int i0 = blockIdx.y * 128, j0 = blockIdx.x * 128;
    int wg = blockIdx.z >> 2, kslice = blockIdx.z & 3;
    const unsigned short* Ah = (wg == 0 ? WwH : TtH) + i0 * 512;
    const unsigned short* Al = (wg == 0 ? WwL : TtL) + i0 * 512;
    const unsigned short* Bh = (wg == 0 ? GtH : PtH) + j0 * 512;
    const unsigned short* Bl = (wg == 0 ? GtL : PtL) + j0 * 512;
    float4v acc[4][4];
#pragma unroll
    for (int m = 0; m < 4; ++m)
#pragma unroll
        for (int n = 0; n < 4; ++n) acc[m][n] = (float4v){0.f, 0.f, 0.f, 0.f};

    mfma_core(Ah, Al, 512, Bh, Bl, 512, lds, acc, kslice * 128, kslice * 128 + 128);

    int lane = threadIdx.x & 63, wave = threadIdx.x >> 6;
    int wm = wave >> 1, wn = wave & 1, l15 = lane & 15, lhi = lane >> 4;
    int rowbase = (wg == 0) ? 512 + i0 : i0;
    float* P = Pw + kslice * 524288;
#pragma unroll
    for (int m = 0; m < 4; ++m)
#pragma unroll
        for (int n = 0; n < 4; ++n) {
            int bcol = j0 + wn * 64 + n * 16 + l15;
#pragma unroll
            for (int i = 0; i < 4; ++i) {
                int r = rowbase + wm * 64 + m * 16 + lhi * 4 + i;
                P[r * 512 + bcol] = acc[m][n][i];
            }
        }
}

// ---------------------------------------------------------------------------
// Partial reduce: MODE 0 split, 1 lrelu+split, 2 lrelu+fp32.
// ---------------------------------------------------------------------------
template <int NPART, int MODE>
__global__ __launch_bounds__(256) void k_red(
    const float* __restrict__ P, int stride,
    unsigned short* __restrict__ Ch, unsigned short* __restrict__ Cl,
    float* __restrict__ Cf) {
    int i4 = blockIdx.x * 256 + threadIdx.x;
    float4v v = ((const float4v*)P)[i4];
#pragma unroll
    for (int p = 1; p < NPART; ++p) {
        float4v u = ((const float4v*)(P + (size_t)p * stride))[i4];
#pragma unroll
        for (int j = 0; j < 4; ++j) v[j] += u[j];
    }
    if (MODE >= 1) {
#pragma unroll
        for (int j = 0; j < 4; ++j) v[j] = lrelu(v[j]);
    }
    if (MODE == 2) {
        ((float4v*)Cf)[i4] = v;
    } else {
        ushort4v h, l;
#pragma unroll
        for (int j = 0; j < 4; ++j) {
            h[j] = f2bf(v[j]);
            l[j] = f2bf(v[j] - bf2f(h[j]));
        }
        ((ushort4v*)Ch)[i4] = h;
        ((ushort4v*)Cl)[i4] = l;
    }
}

// ---------------------------------------------------------------------------
// Stage A via MFMA: grid (48, 8): x = b*3+kin, y = o-tile
// ---------------------------------------------------------------------------
__global__ __launch_bounds__(256) void k_ga(
    const unsigned short* __restrict__ Whi, const unsigned short* __restrict__ Wlo,
    const unsigned short* __restrict__ Xh, const unsigned short* __restrict__ Xl,
    unsigned short* __restrict__ Yh, unsigned short* __restrict__ Yl,
    float* __restrict__ Wg) {
    __shared__ unsigned short lds[32768];
    int bk = blockIdx.x, y = blockIdx.y;
    int b = bk / 3, kin = bk - b * 3;
    int bbase = (b * 384 + kin) * 512;
    float4v acc[4][4];
#pragma unroll
    for (int m = 0; m < 4; ++m)
#pragma unroll
        for (int n = 0; n < 4; ++n) acc[m][n] = (float4v){0.f, 0.f, 0.f, 0.f};

    mfma_core(Whi + y * 128 * 512, Wlo + y * 128 * 512, 512,
              Xh + bbase, Xl + bbase, 1536, lds, acc, 0, 512);

    int lane = threadIdx.x & 63, wave = threadIdx.x >> 6;
    int wm = wave >> 1, wn = wave & 1, l15 = lane & 15, lhi = lane >> 4;
    int wsel = y >> 2, o0 = (y & 3) * 128;
#pragma unroll
    for (int m = 0; m < 4; ++m)
#pragma unroll
        for (int n = 0; n < 4; ++n) {
            int o_in = wm * 64 + m * 16 + lhi * 4;
            int t = wn * 64 + n * 16 + l15;
            int idx = bbase + t * 1536 + o0 + o_in;
            if (wsel == 1) {
                *(float4v*)&Wg[idx] = acc[m][n];
            } else {
                ushort4v h, l;
#pragma unroll
                for (int i = 0; i < 4; ++i) {
                    float v = acc[m][n][i];
                    h[i] = f2bf(v);
                    l[i] = f2bf(v - bf2f(h[i]));
                }
                *(ushort4v*)&Yh[idx] = h;
                *(ushort4v*)&Yl[idx] = l;
            }
        }
}

// ---------------------------------------------------------------------------
// Band gram: |t1-t2|<=7 only. grid 1152 XCD-swizzled, block 64.
// ---------------------------------------------------------------------------
__global__ __launch_bounds__(64) void k_gram3(
    const unsigned short* __restrict__ Xh, const unsigned short* __restrict__ Xl,
    const unsigned short* __restrict__ Yh, const unsigned short* __restrict__ Yl,
    float* __restrict__ D) {
    __shared__ unsigned short lds[8192];
    int orig = blockIdx.x;
    int idx = (orig & 7) * 144 + (orig >> 3);
    int mat = idx >> 3, c = idx & 7;
    int b = mat / 9, r9 = mat - b * 9, k = r9 / 3, kp = r9 - k * 3;
    const unsigned short* Ahg = Xh + (b * 384 + k) * 512;
    const unsigned short* Alg = Xl + (b * 384 + k) * 512;
    const unsigned short* Bhg = Yh + (b * 384 + kp) * 512;
    const unsigned short* Blg = Yl + (b * 384 + kp) * 512;
    int t1b = c * 16, t2b0 = c * 16 - 16;
    unsigned short* LAh = lds;
    unsigned short* LAl = lds + 1024;
    unsigned short* LBh = lds + 2048;
    unsigned short* LBl = lds + 5120;
    int tid = threadIdx.x;
    int l15 = tid & 15, lhi = tid >> 4;
    float4v acc[3];
    acc[0] = (float4v){0.f, 0.f, 0.f, 0.f};
    acc[1] = (float4v){0.f, 0.f, 0.f, 0.f};
    acc[2] = (float4v){0.f, 0.f, 0.f, 0.f};

    for (int k0 = 0; k0 < 512; k0 += 64) {
#pragma unroll
        for (int it = 0; it < 2; ++it) {
            int i2 = it * 64 + tid;
            int row = i2 >> 3, ch = i2 & 7;
            int g = (t1b + row) * 1536 + k0 + ((ch ^ (row & 7)) << 3);
            gload16(&Ahg[g], LAh + ((it * 64) << 3));
            gload16(&Alg[g], LAl + ((it * 64) << 3));
        }
#pragma unroll
        for (int it = 0; it < 6; ++it) {
            int i2 = it * 64 + tid;
            int row = i2 >> 3, ch = i2 & 7;
            int t2 = t2b0 + row;
            int t2c = t2 < 0 ? 0 : (t2 > 127 ? 127 : t2);
            int g = t2c * 1536 + k0 + ((ch ^ (row & 7)) << 3);
            gload16(&Bhg[g], LBh + ((it * 64) << 3));
            gload16(&Blg[g], LBl + ((it * 64) << 3));
        }
        __syncthreads();
#pragma unroll
        for (int ks = 0; ks < 2; ++ks) {
            int offa = l15 * 64 + (((ks * 4 + lhi) ^ (l15 & 7)) * 8);
            short8 ah = *(const short8*)&LAh[offa];
            short8 al = *(const short8*)&LAl[offa];
#pragma unroll
            for (int tl = 0; tl < 3; ++tl) {
                int rb = tl * 16 + l15;
                int offb = rb * 64 + (((ks * 4 + lhi) ^ (rb & 7)) * 8);
                short8 bh = *(const short8*)&LBh[offb];
                short8 bl = *(const short8*)&LBl[offb];
                acc[tl] = __builtin_amdgcn_mfma_f32_16x16x32_bf16(ah, bh, acc[tl], 0, 0, 0);
                acc[tl] = __builtin_amdgcn_mfma_f32_16x16x32_bf16(ah, bl, acc[tl], 0, 0, 0);
                acc[tl] = __builtin_amdgcn_mfma_f32_16x16x32_bf16(al, bh, acc[tl], 0, 0, 0);
            }
        }
        __syncthreads();
    }
    float* Dm = D + mat * 16384;
#pragma unroll
    for (int tl = 0; tl < 3; ++tl) {
        int t2base = t2b0 + tl * 16;
        if (t2base < 0 || t2base > 127) continue;
        int t2 = t2base + l15;
#pragma unroll
        for (int i = 0; i < 4; ++i) {
            int t1 = t1b + lhi * 4 + i;
            Dm[t1 * 128 + t2] = acc[tl][i];
        }
    }
}

// ---------------------------------------------------------------------------
// MLP layer, split-K=2: grid (16,4,2). Partials; activation in k_red.
// ---------------------------------------------------------------------------
__global__ __launch_bounds__(256) void k_mlp_sk(
    const unsigned short* __restrict__ Ahi, const unsigned short* __restrict__ Alo,
    const unsigned short* __restrict__ Bhi, const unsigned short* __restrict__ Blo,
    float* __restrict__ Pp) {
    __shared__ unsigned short lds[32768];
    int r0 = blockIdx.x * 128, o0 = blockIdx.y * 128;
    int kslice = blockIdx.z;
    float4v acc[4][4];
#pragma unroll
    for (int m = 0; m < 4; ++m)
#pragma unroll
        for (int n = 0; n < 4; ++n) acc[m][n] = (float4v){0.f, 0.f, 0.f, 0.f};

    mfma_core(Ahi + r0 * 512, Alo + r0 * 512, 512, Bhi + o0 * 512, Blo + o0 * 512, 512,
              lds, acc, kslice * 256, kslice * 256 + 256);

    int lane = threadIdx.x & 63, wave = threadIdx.x >> 6;
    int wm = wave >> 1, wn = wave & 1, l15 = lane & 15, lhi = lane >> 4;
    float* P = Pp + (size_t)kslice * 1048576;
#pragma unroll
    for (int m = 0; m < 4; ++m)
#pragma unroll
        for (int n = 0; n < 4; ++n) {
            int o = o0 + wn * 64 + n * 16 + l15;
#pragma unroll
            for (int i = 0; i < 4; ++i) {
                int r = r0 + wm * 64 + m * 16 + lhi * 4 + i;
                P[r * 512 + o] = acc[m][n][i];
            }
        }
}

// ---------------------------------------------------------------------------
// Mix, 8 t's per block (r16): union window 15 slots x 3, softmax 192-way.
// grid 256 XCD-swizzled, block 512, one o per thread. Per-t math identical.
// ---------------------------------------------------------------------------
__global__ __launch_bounds__(512) void k_mix(
    const float* __restrict__ Xf, const float* __restrict__ Wg,
    const float* __restrict__ D, const float* __restrict__ W_b,
    unsigned short* __restrict__ Plh, unsigned short* __restrict__ Pll) {
    int orig = blockIdx.x;
    int bid = ((orig & 7) << 5) | (orig >> 3);  // 256 = 8 * 32, bijective
    int b = bid >> 4, tg = bid & 15;
    int t0 = tg * 8;
    int tid = threadIdx.x;

    __shared__ float Pm[8][24][28];

    // gather f for 8 t's
    for (int idx = tid; idx < 8 * 576; idx += 512) {
        int dt = idx / 576, r = idx - dt * 576;
        int n = r / 24, m = r - n * 24;
        int t = t0 + dt;
        int j = n / 3, k = n - j * 3;
        int jp = m / 3, kp = m - jp * 3;
        int t1 = t - 7 + j, t2 = t - 7 + jp;
        float v = 0.f;
        if (t1 >= 0 && t2 >= 0)
            v = D[((((b * 3 + k) * 3 + kp) * 128 + t1) << 7) + t2];
        Pm[dt][n][m] = v;
    }
    __syncthreads();

    // softmax: 192 rows in parallel
    if (tid < 192) {
        int dt = tid / 24, n = tid - dt * 24;
        float mx = -1e30f;
#pragma unroll
        for (int m = 0; m < 24; ++m) mx = fmaxf(mx, Pm[dt][n][m]);
        float e[24], sum = 0.f;
#pragma unroll
        for (int m = 0; m < 24; ++m) { e[m] = __expf(Pm[dt][n][m] - mx); sum += e[m]; }
        float inv = 1.0f / sum;
#pragma unroll
        for (int m = 0; m < 24; ++m) Pm[dt][n][m] = e[m] * inv;
    }
    __syncthreads();

    int o = tid;
    // union preload: slot s <-> tp = t0 - 7 + s, s in [0, 14], x3 k
    float wg[45], xw[45];
#pragma unroll
    for (int s = 0; s < 15; ++s) {
        int tp = t0 - 7 + s;
#pragma unroll
        for (int k = 0; k < 3; ++k) {
            int base = (((b * 128 + tp) * 3 + k) << 9) + o;
            bool ok = (tp >= 0);
            wg[s * 3 + k] = ok ? Wg[base] : 0.f;
            xw[s * 3 + k] = ok ? Xf[base] : 0.f;
        }
    }
    float wb = W_b[o];
#pragma unroll
    for (int dt = 0; dt < 8; ++dt) {
        float pooled = -1e30f;
#pragma unroll
        for (int n = 0; n < 24; ++n) {
            float s0 = 0.f, s1 = 0.f, s2 = 0.f, s3 = 0.f;
#pragma unroll
            for (int mq = 0; mq < 6; ++mq) {
                float4 p4 = *(const float4*)&Pm[dt][n][mq * 4];
                s0 += p4.x * wg[mq * 4 + 0 + dt * 3];
                s1 += p4.y * wg[mq * 4 + 1 + dt * 3];
                s2 += p4.z * wg[mq * 4 + 2 + dt * 3];
                s3 += p4.w * wg[mq * 4 + 3 + dt * 3];
            }
            float s = ((s0 + s1) + (s2 + s3)) + wb + xw[n + dt * 3];
            pooled = fmaxf(pooled, s);
        }
        int t = t0 + dt;
        int oidx = ((t * 16 + b) << 9) + o;
        unsigned short h = f2bf(pooled), l = f2bf(pooled - bf2f(h));
        Plh[oidx] = h;
        Pll[oidx] = l;
    }
}

// ---------------------------------------------------------------------------
// out[r] = lrelu( sum_c H[r][c]*p3w[c] + p3b )   one wave per row
// ---------------------------------------------------------------------------
__global__ __launch_bounds__(256) void k_final(const float* __restrict__ H,
                                               const float* __restrict__ p3w,
                                               const float* __restrict__ p3b,
                                               float* __restrict__ out) {
    int r = blockIdx.x * 4 + (threadIdx.x >> 6);
    int lane = threadIdx.x & 63;
    const float4* h4 = (const float4*)&H[r << 9];
    const float4* w4 = (const float4*)p3w;
    float4 a1 = h4[lane], a2 = h4[lane + 64];
    float4 b1 = w4[lane], b2 = w4[lane + 64];
    float s = a1.x * b1.x + a1.y * b1.y + a1.z * b1.z + a1.w * b1.w +
              a2.x * b2.x + a2.y * b2.y + a2.z * b2.z + a2.w * b2.w;
#pragma unroll
    for (int off = 32; off; off >>= 1) s += __shfl_down(s, off, 64);
    if (lane == 0) out[r] = lrelu(s + p3b[0]);
}

extern "C" void kernel_launch(void* const* d_in, const int* in_sizes, int n_in,
                              void* d_out, int out_size, void* d_ws, size_t ws_size,
                              hipStream_t stream) {
    const float* out1 = (const float*)d_in[0];
    const float* out2 = (const float*)d_in[1];
    const float* out3 = (const float*)d_in[2];
    const float* theta_w = (const float*)d_in[3];
    const float* phi_w = (const float*)d_in[4];
    const float* g_w = (const float*)d_in[5];
    const float* W_w = (const float*)d_in[6];
    const float* W_b = (const float*)d_in[7];
    const float* p1_w = (const float*)d_in[8];
    const float* p2_w = (const float*)d_in[9];
    const float* p3_w = (const float*)d_in[10];
    const float* p3_b = (const float*)d_in[11];
    float* outp = (float*)d_out;

    // ---- workspace layout (bytes) ----
    char* wsb = (char*)d_ws;
    unsigned short* Whi = (unsigned short*)(wsb + 0);         // 1024x512 bf16 (Mw | Wg_w)
    unsigned short* Wlo = (unsigned short*)(wsb + 1048576);
    unsigned short* p1h = (unsigned short*)(wsb + 2097152);
    unsigned short* p1l = (unsigned short*)(wsb + 2621440);
    unsigned short* p2h = (unsigned short*)(wsb + 3145728);
    unsigned short* p2l = (unsigned short*)(wsb + 3670016);
    unsigned short* WwH = (unsigned short*)(wsb + 4194304);
    unsigned short* WwL = (unsigned short*)(wsb + 4718592);
    unsigned short* TtH = (unsigned short*)(wsb + 5242880);
    unsigned short* TtL = (unsigned short*)(wsb + 5767168);
    unsigned short* PtH = (unsigned short*)(wsb + 6291456);
    unsigned short* PtL = (unsigned short*)(wsb + 6815744);
    unsigned short* GtH = (unsigned short*)(wsb + 7340032);
    unsigned short* GtL = (unsigned short*)(wsb + 7864320);
    unsigned short* Xh  = (unsigned short*)(wsb + 8388608);   // 6144x512 bf16
    unsigned short* Xl  = (unsigned short*)(wsb + 14680064);
    unsigned short* Yh  = (unsigned short*)(wsb + 20971520);  // 6144x512 bf16
    unsigned short* Yl  = (unsigned short*)(wsb + 27262976);
    float* Wg = (float*)(wsb + 33554432);                     // 6144x512 fp32 (wgemm partials pre-k_ga)
    float* D  = (float*)(wsb + 46137344);                     // 144x128x128 fp32 (MLP partials post-k_mix)
    float* Xf = (float*)(wsb + 55574528);                     // 6144x512 fp32
    // aliases (dead-buffer reuse):
    float* Pw = Wg;
    float* Pp = D;
    unsigned short* Plh = (unsigned short*)(wsb + 20971520);  // over Yh (dead after gram)
    unsigned short* Pll = (unsigned short*)(wsb + 23068672);
    unsigned short* h1h = (unsigned short*)(wsb + 27262976);  // over Yl (dead after gram)
    unsigned short* h1l = (unsigned short*)(wsb + 29360128);
    float* h2 = (float*)(wsb + 8388608);                      // over Xh (dead after mix)

    // 1. all splits fused (weights + inputs)
    k_split_all<<<dim3(4608), dim3(32, 8), 0, stream>>>(
        theta_w, phi_w, g_w, W_w, p1_w, p2_w, out1, out2, out3,
        TtH, TtL, PtH, PtL, GtH, GtL, WwH, WwL, p1h, p1l, p2h, p2l,
        Xh, Xl, Xf);
    // 2. weight GEMMs split-K=4 -> reduce+split into Whi/Wlo
    k_wgemm_sk<<<dim3(4, 4, 8), 256, 0, stream>>>(WwH, WwL, GtH, GtL, TtH, TtL,
                                                  PtH, PtL, Pw);
    k_red<4, 0><<<dim3(512), 256, 0, stream>>>(Pw, 524288, Whi, Wlo, nullptr);
    // 3. stage A: Y (bf16 hi/lo) + Wg (fp32)
    k_ga<<<dim3(48, 8), 256, 0, stream>>>(Whi, Wlo, Xh, Xl, Yh, Yl, Wg);
    // 4. band gram matrices
    k_gram3<<<dim3(1152), 64, 0, stream>>>(Xh, Xl, Yh, Yl, D);
    // 5. softmax + mix + residual + pool (8 t's per block)
    k_mix<<<dim3(256), 512, 0, stream>>>(Xf, Wg, D, W_b, Plh, Pll);
    // 6. MLP1 split-K=2 -> reduce+lrelu+split
    k_mlp_sk<<<dim3(16, 4, 2), 256, 0, stream>>>(Plh, Pll, p1h, p1l, Pp);
    k_red<2, 1><<<dim3(1024), 256, 0, stream>>>(Pp, 1048576, h1h, h1l, nullptr);
    // 7. MLP2 split-K=2 -> reduce+lrelu -> h2 fp32
    k_mlp_sk<<<dim3(16, 4, 2), 256, 0, stream>>>(h1h, h1l, p2h, p2l, Pp);
    k_red<2, 2><<<dim3(1024), 256, 0, stream>>>(Pp, 1048576, nullptr, nullptr, h2);
    // 8. final projection
    k_final<<<dim3(512), 256, 0, stream>>>(h2, p3_w, p3_b, outp);
}

// Round 17
// 119.162 us; speedup vs baseline: 1.0684x; 1.0684x over previous
//
#include <hip/hip_runtime.h>

typedef __attribute__((ext_vector_type(8))) short short8;
typedef __attribute__((ext_vector_type(4))) float float4v;
typedef __attribute__((ext_vector_type(4))) unsigned int uint4v;
typedef __attribute__((ext_vector_type(4))) unsigned short ushort4v;

__device__ __forceinline__ float lrelu(float v) { return v >= 0.f ? v : 0.01f * v; }

__device__ __forceinline__ unsigned short f2bf(float x) {
    union { float f; unsigned u; } c; c.f = x;
    unsigned r = (c.u + 0x7FFFu + ((c.u >> 16) & 1u)) >> 16;
    return (unsigned short)r;
}
__device__ __forceinline__ float bf2f(unsigned short h) {
    union { unsigned u; float f; } c; c.u = ((unsigned)h) << 16;
    return c.f;
}

// async global->LDS, 16B per lane. LDS dest must be wave-uniform base
// (HW adds lane*16); global src is per-lane (pre-swizzled).
__device__ __forceinline__ void gload16(const unsigned short* g, unsigned short* l) {
    __builtin_amdgcn_global_load_lds(
        (const __attribute__((address_space(1))) unsigned int*)g,
        (__attribute__((address_space(3))) unsigned int*)l, 16, 0, 0);
}

// ===========================================================================
// Shared MFMA core (K-range for split-K): C[128x128] += A.B^T over
// K in [kBeg,kEnd), split-bf16 (hh+hl+lh ~ fp32). 256 threads, 4 waves 2x2.
// LDS: 4 tiles [128][64]. gload_lds direct staging, both-sides XOR swizzle.
// ===========================================================================
__device__ __forceinline__ void mfma_core(
    const unsigned short* __restrict__ Ah, const unsigned short* __restrict__ Al, int lda,
    const unsigned short* __restrict__ Bh, const unsigned short* __restrict__ Bl, int ldb,
    unsigned short* lds, float4v acc[4][4], int kBeg, int kEnd) {
    const int tid = threadIdx.x;
    const int lane = tid & 63, wave = tid >> 6;
    const int wm = wave >> 1, wn = wave & 1;
    const int l15 = lane & 15, lhi = lane >> 4;
    unsigned short* LAh = lds;
    unsigned short* LAl = lds + 8192;
    unsigned short* LBh = lds + 16384;
    unsigned short* LBl = lds + 24576;

    for (int k0 = kBeg; k0 < kEnd; k0 += 64) {
#pragma unroll
        for (int tile = 0; tile < 4; ++tile) {
            const unsigned short* s = (tile == 0) ? Ah : (tile == 1) ? Al : (tile == 2) ? Bh : Bl;
            int ld = (tile < 2) ? lda : ldb;
            unsigned short* dbase = lds + tile * 8192;
#pragma unroll
            for (int it = 0; it < 4; ++it) {
                int idx = it * 256 + tid;
                int row = idx >> 3, ch = idx & 7;
                gload16(&s[row * ld + k0 + ((ch ^ (row & 7)) << 3)],
                        dbase + ((it * 256 + wave * 64) << 3));
            }
        }
        __syncthreads();
#pragma unroll
        for (int ks = 0; ks < 2; ++ks) {
            short8 ah[4], al[4], bh[4], bl[4];
#pragma unroll
            for (int m = 0; m < 4; ++m) {
                int r = wm * 64 + m * 16 + l15;
                int off = r * 64 + (((ks * 4 + lhi) ^ (r & 7)) * 8);
                ah[m] = *(const short8*)&LAh[off];
                al[m] = *(const short8*)&LAl[off];
            }
#pragma unroll
            for (int n = 0; n < 4; ++n) {
                int r = wn * 64 + n * 16 + l15;
                int off = r * 64 + (((ks * 4 + lhi) ^ (r & 7)) * 8);
                bh[n] = *(const short8*)&LBh[off];
                bl[n] = *(const short8*)&LBl[off];
            }
#pragma unroll
            for (int m = 0; m < 4; ++m)
#pragma unroll
                for (int n = 0; n < 4; ++n) {
                    acc[m][n] = __builtin_amdgcn_mfma_f32_16x16x32_bf16(ah[m], bh[n], acc[m][n], 0, 0, 0);
                    acc[m][n] = __builtin_amdgcn_mfma_f32_16x16x32_bf16(ah[m], bl[n], acc[m][n], 0, 0, 0);
                    acc[m][n] = __builtin_amdgcn_mfma_f32_16x16x32_bf16(al[m], bh[n], acc[m][n], 0, 0, 0);
                }
        }
        __syncthreads();
    }
}

// ---------------------------------------------------------------------------
// Fused ALL splits: flat grid 4608, block (32,8).
//   bz < 1536: weight splits (0-2 transpose theta/phi/g; 3-5 straight).
//   bz >= 1536: input transpose+split (Xh/Xl/Xf).
// ---------------------------------------------------------------------------
__global__ __launch_bounds__(256) void k_split_all(
    const float* __restrict__ tw, const float* __restrict__ fw,
    const float* __restrict__ gw, const float* __restrict__ ww,
    const float* __restrict__ p1w, const float* __restrict__ p2w,
    const float* __restrict__ o1, const float* __restrict__ o2,
    const float* __restrict__ o3,
    unsigned short* __restrict__ TtH, unsigned short* __restrict__ TtL,
    unsigned short* __restrict__ PtH, unsigned short* __restrict__ PtL,
    unsigned short* __restrict__ GtH, unsigned short* __restrict__ GtL,
    unsigned short* __restrict__ WwH, unsigned short* __restrict__ WwL,
    unsigned short* __restrict__ p1h, unsigned short* __restrict__ p1l,
    unsigned short* __restrict__ p2h, unsigned short* __restrict__ p2l,
    unsigned short* __restrict__ Xh, unsigned short* __restrict__ Xl,
    float* __restrict__ Xf) {
    int bz = blockIdx.x;
    int tx = threadIdx.x, ty = threadIdx.y;
    __shared__ float tile[32][33];
    if (bz < 1536) {
        int z = bz >> 8, rem = bz & 255;
        int by = rem >> 4, bx = rem & 15;
        int i0 = bx * 32, k0 = by * 32;
        if (z < 3) {
            const float* src = (z == 0) ? tw : (z == 1) ? fw : gw;
            unsigned short* dh = (z == 0) ? TtH : (z == 1) ? PtH : GtH;
            unsigned short* dl = (z == 0) ? TtL : (z == 1) ? PtL : GtL;
#pragma unroll
            for (int i = 0; i < 4; ++i)
                tile[ty + i * 8][tx] = src[(k0 + ty + i * 8) * 512 + i0 + tx];
            __syncthreads();
#pragma unroll
            for (int i = 0; i < 4; ++i) {
                int row = i0 + ty + i * 8;
                float v = tile[tx][ty + i * 8];
                unsigned short h = f2bf(v), l = f2bf(v - bf2f(h));
                int idx = row * 512 + k0 + tx;
                dh[idx] = h;
                dl[idx] = l;
            }
        } else {
            const float* src = (z == 3) ? ww : (z == 4) ? p1w : p2w;
            unsigned short* dh = (z == 3) ? WwH : (z == 4) ? p1h : p2h;
            unsigned short* dl = (z == 3) ? WwL : (z == 4) ? p1l : p2l;
#pragma unroll
            for (int i = 0; i < 4; ++i) {
                int r = k0 + ty + i * 8;
                int idx = r * 512 + i0 + tx;
                float v = src[idx];
                unsigned short h = f2bf(v), l = f2bf(v - bf2f(h));
                dh[idx] = h;
                dl[idx] = l;
            }
        }
    } else {
        int r = bz - 1536;
        int z = r >> 6, rem = r & 63;
        int by = rem >> 4, bx = rem & 15;
        int b = z / 3, k = z - b * 3;
        const float* In = (k == 0) ? o1 : ((k == 1) ? o2 : o3);
        int c0 = bx * 32, t0 = by * 32;
#pragma unroll
        for (int i = 0; i < 4; ++i)
            tile[ty + i * 8][tx] = In[(b * 512 + c0 + ty + i * 8) * 128 + t0 + tx];
        __syncthreads();
#pragma unroll
        for (int i = 0; i < 4; ++i) {
            int t = t0 + ty + i * 8;
            float v = tile[tx][ty + i * 8];
            unsigned short h = f2bf(v), l = f2bf(v - bf2f(h));
            int idx = ((b * 128 + t) * 3 + k) * 512 + c0 + tx;
            Xh[idx] = h;
            Xl[idx] = l;
            Xf[idx] = v;
        }
    }
}

// ---------------------------------------------------------------------------
// Weight GEMMs, split-K=4: grid (4,4,8): z = wg*4 + kslice.
// ---------------------------------------------------------------------------
__global__ __launch_bounds__(256) void k_wgemm_sk(
    const unsigned short* __restrict__ WwH, const unsigned short* __restrict__ WwL,
    const unsigned short* __restrict__ GtH, const unsigned short* __restrict__ GtL,
    const unsigned short* __restrict__ TtH, const unsigned short* __restrict__ TtL,
    const unsigned short* __restrict__ PtH, const unsigned short* __restrict__ PtL,
    float* __restrict__ Pw) {
    __shared__ unsigned short lds[32768];
    int i0 = blockIdx.y * 128, j0 = blockIdx.x * 128;
    int wg = blockIdx.z >> 2, kslice = blockIdx.z & 3;
    const unsigned short* Ah = (wg == 0 ? WwH : TtH) + i0 * 512;
    const unsigned short* Al = (wg == 0 ? WwL : TtL) + i0 * 512;
    const unsigned short* Bh = (wg == 0 ? GtH : PtH) + j0 * 512;
    const unsigned short* Bl = (wg == 0 ? GtL : PtL) + j0 * 512;
    float4v acc[4][4];
#pragma unroll
    for (int m = 0; m < 4; ++m)
#pragma unroll
        for (int n = 0; n < 4; ++n) acc[m][n] = (float4v){0.f, 0.f, 0.f, 0.f};

    mfma_core(Ah, Al, 512, Bh, Bl, 512, lds, acc, kslice * 128, kslice * 128 + 128);

    int lane = threadIdx.x & 63, wave = threadIdx.x >> 6;
    int wm = wave >> 1, wn = wave & 1, l15 = lane & 15, lhi = lane >> 4;
    int rowbase = (wg == 0) ? 512 + i0 : i0;
    float* P = Pw + kslice * 524288;
#pragma unroll
    for (int m = 0; m < 4; ++m)
#pragma unroll
        for (int n = 0; n < 4; ++n) {
            int bcol = j0 + wn * 64 + n * 16 + l15;
#pragma unroll
            for (int i = 0; i < 4; ++i) {
                int r = rowbase + wm * 64 + m * 16 + lhi * 4 + i;
                P[r * 512 + bcol] = acc[m][n][i];
            }
        }
}

// ---------------------------------------------------------------------------
// Partial reduce: MODE 0 split, 1 lrelu+split, 2 lrelu+fp32.
// ---------------------------------------------------------------------------
template <int NPART, int MODE>
__global__ __launch_bounds__(256) void k_red(
    const float* __restrict__ P, int stride,
    unsigned short* __restrict__ Ch, unsigned short* __restrict__ Cl,
    float* __restrict__ Cf) {
    int i4 = blockIdx.x * 256 + threadIdx.x;
    float4v v = ((const float4v*)P)[i4];
#pragma unroll
    for (int p = 1; p < NPART; ++p) {
        float4v u = ((const float4v*)(P + (size_t)p * stride))[i4];
#pragma unroll
        for (int j = 0; j < 4; ++j) v[j] += u[j];
    }
    if (MODE >= 1) {
#pragma unroll
        for (int j = 0; j < 4; ++j) v[j] = lrelu(v[j]);
    }
    if (MODE == 2) {
        ((float4v*)Cf)[i4] = v;
    } else {
        ushort4v h, l;
#pragma unroll
        for (int j = 0; j < 4; ++j) {
            h[j] = f2bf(v[j]);
            l[j] = f2bf(v[j] - bf2f(h[j]));
        }
        ((ushort4v*)Ch)[i4] = h;
        ((ushort4v*)Cl)[i4] = l;
    }
}

// ---------------------------------------------------------------------------
// Stage A via MFMA: grid (48, 8): x = b*3+kin, y = o-tile
// ---------------------------------------------------------------------------
__global__ __launch_bounds__(256) void k_ga(
    const unsigned short* __restrict__ Whi, const unsigned short* __restrict__ Wlo,
    const unsigned short* __restrict__ Xh, const unsigned short* __restrict__ Xl,
    unsigned short* __restrict__ Yh, unsigned short* __restrict__ Yl,
    float* __restrict__ Wg) {
    __shared__ unsigned short lds[32768];
    int bk = blockIdx.x, y = blockIdx.y;
    int b = bk / 3, kin = bk - b * 3;
    int bbase = (b * 384 + kin) * 512;
    float4v acc[4][4];
#pragma unroll
    for (int m = 0; m < 4; ++m)
#pragma unroll
        for (int n = 0; n < 4; ++n) acc[m][n] = (float4v){0.f, 0.f, 0.f, 0.f};

    mfma_core(Whi + y * 128 * 512, Wlo + y * 128 * 512, 512,
              Xh + bbase, Xl + bbase, 1536, lds, acc, 0, 512);

    int lane = threadIdx.x & 63, wave = threadIdx.x >> 6;
    int wm = wave >> 1, wn = wave & 1, l15 = lane & 15, lhi = lane >> 4;
    int wsel = y >> 2, o0 = (y & 3) * 128;
#pragma unroll
    for (int m = 0; m < 4; ++m)
#pragma unroll
        for (int n = 0; n < 4; ++n) {
            int o_in = wm * 64 + m * 16 + lhi * 4;
            int t = wn * 64 + n * 16 + l15;
            int idx = bbase + t * 1536 + o0 + o_in;
            if (wsel == 1) {
                *(float4v*)&Wg[idx] = acc[m][n];
            } else {
                ushort4v h, l;
#pragma unroll
                for (int i = 0; i < 4; ++i) {
                    float v = acc[m][n][i];
                    h[i] = f2bf(v);
                    l[i] = f2bf(v - bf2f(h[i]));
                }
                *(ushort4v*)&Yh[idx] = h;
                *(ushort4v*)&Yl[idx] = l;
            }
        }
}

// ---------------------------------------------------------------------------
// Band gram: |t1-t2|<=7 only. grid 1152 XCD-swizzled, block 64.
// ---------------------------------------------------------------------------
__global__ __launch_bounds__(64) void k_gram3(
    const unsigned short* __restrict__ Xh, const unsigned short* __restrict__ Xl,
    const unsigned short* __restrict__ Yh, const unsigned short* __restrict__ Yl,
    float* __restrict__ D) {
    __shared__ unsigned short lds[8192];
    int orig = blockIdx.x;
    int idx = (orig & 7) * 144 + (orig >> 3);
    int mat = idx >> 3, c = idx & 7;
    int b = mat / 9, r9 = mat - b * 9, k = r9 / 3, kp = r9 - k * 3;
    const unsigned short* Ahg = Xh + (b * 384 + k) * 512;
    const unsigned short* Alg = Xl + (b * 384 + k) * 512;
    const unsigned short* Bhg = Yh + (b * 384 + kp) * 512;
    const unsigned short* Blg = Yl + (b * 384 + kp) * 512;
    int t1b = c * 16, t2b0 = c * 16 - 16;
    unsigned short* LAh = lds;
    unsigned short* LAl = lds + 1024;
    unsigned short* LBh = lds + 2048;
    unsigned short* LBl = lds + 5120;
    int tid = threadIdx.x;
    int l15 = tid & 15, lhi = tid >> 4;
    float4v acc[3];
    acc[0] = (float4v){0.f, 0.f, 0.f, 0.f};
    acc[1] = (float4v){0.f, 0.f, 0.f, 0.f};
    acc[2] = (float4v){0.f, 0.f, 0.f, 0.f};

    for (int k0 = 0; k0 < 512; k0 += 64) {
#pragma unroll
        for (int it = 0; it < 2; ++it) {
            int i2 = it * 64 + tid;
            int row = i2 >> 3, ch = i2 & 7;
            int g = (t1b + row) * 1536 + k0 + ((ch ^ (row & 7)) << 3);
            gload16(&Ahg[g], LAh + ((it * 64) << 3));
            gload16(&Alg[g], LAl + ((it * 64) << 3));
        }
#pragma unroll
        for (int it = 0; it < 6; ++it) {
            int i2 = it * 64 + tid;
            int row = i2 >> 3, ch = i2 & 7;
            int t2 = t2b0 + row;
            int t2c = t2 < 0 ? 0 : (t2 > 127 ? 127 : t2);
            int g = t2c * 1536 + k0 + ((ch ^ (row & 7)) << 3);
            gload16(&Bhg[g], LBh + ((it * 64) << 3));
            gload16(&Blg[g], LBl + ((it * 64) << 3));
        }
        __syncthreads();
#pragma unroll
        for (int ks = 0; ks < 2; ++ks) {
            int offa = l15 * 64 + (((ks * 4 + lhi) ^ (l15 & 7)) * 8);
            short8 ah = *(const short8*)&LAh[offa];
            short8 al = *(const short8*)&LAl[offa];
#pragma unroll
            for (int tl = 0; tl < 3; ++tl) {
                int rb = tl * 16 + l15;
                int offb = rb * 64 + (((ks * 4 + lhi) ^ (rb & 7)) * 8);
                short8 bh = *(const short8*)&LBh[offb];
                short8 bl = *(const short8*)&LBl[offb];
                acc[tl] = __builtin_amdgcn_mfma_f32_16x16x32_bf16(ah, bh, acc[tl], 0, 0, 0);
                acc[tl] = __builtin_amdgcn_mfma_f32_16x16x32_bf16(ah, bl, acc[tl], 0, 0, 0);
                acc[tl] = __builtin_amdgcn_mfma_f32_16x16x32_bf16(al, bh, acc[tl], 0, 0, 0);
            }
        }
        __syncthreads();
    }
    float* Dm = D + mat * 16384;
#pragma unroll
    for (int tl = 0; tl < 3; ++tl) {
        int t2base = t2b0 + tl * 16;
        if (t2base < 0 || t2base > 127) continue;
        int t2 = t2base + l15;
#pragma unroll
        for (int i = 0; i < 4; ++i) {
            int t1 = t1b + lhi * 4 + i;
            Dm[t1 * 128 + t2] = acc[tl][i];
        }
    }
}

// ---------------------------------------------------------------------------
// MLP layer, split-K=2: grid (16,4,2). Partials; activation in k_red.
// ---------------------------------------------------------------------------
__global__ __launch_bounds__(256) void k_mlp_sk(
    const unsigned short* __restrict__ Ahi, const unsigned short* __restrict__ Alo,
    const unsigned short* __restrict__ Bhi, const unsigned short* __restrict__ Blo,
    float* __restrict__ Pp) {
    __shared__ unsigned short lds[32768];
    int r0 = blockIdx.x * 128, o0 = blockIdx.y * 128;
    int kslice = blockIdx.z;
    float4v acc[4][4];
#pragma unroll
    for (int m = 0; m < 4; ++m)
#pragma unroll
        for (int n = 0; n < 4; ++n) acc[m][n] = (float4v){0.f, 0.f, 0.f, 0.f};

    mfma_core(Ahi + r0 * 512, Alo + r0 * 512, 512, Bhi + o0 * 512, Blo + o0 * 512, 512,
              lds, acc, kslice * 256, kslice * 256 + 256);

    int lane = threadIdx.x & 63, wave = threadIdx.x >> 6;
    int wm = wave >> 1, wn = wave & 1, l15 = lane & 15, lhi = lane >> 4;
    float* P = Pp + (size_t)kslice * 1048576;
#pragma unroll
    for (int m = 0; m < 4; ++m)
#pragma unroll
        for (int n = 0; n < 4; ++n) {
            int o = o0 + wn * 64 + n * 16 + l15;
#pragma unroll
            for (int i = 0; i < 4; ++i) {
                int r = r0 + wm * 64 + m * 16 + lhi * 4 + i;
                P[r * 512 + o] = acc[m][n][i];
            }
        }
}

// ---------------------------------------------------------------------------
// Mix, 4 t's per block (r15 proven body, reverted from r16's 8-t):
// gather band f, softmax (96-way), union preload 11 slots x 3, float4 Pm.
// grid 512 XCD-swizzled, block 512, one o per thread.
// ---------------------------------------------------------------------------
__global__ __launch_bounds__(512) void k_mix(
    const float* __restrict__ Xf, const float* __restrict__ Wg,
    const float* __restrict__ D, const float* __restrict__ W_b,
    unsigned short* __restrict__ Plh, unsigned short* __restrict__ Pll) {
    int orig = blockIdx.x;
    int bid = ((orig & 7) << 6) | (orig >> 3);  // 512 = 8 * 64, bijective
    int b = bid >> 5, tg = bid & 31;
    int t0 = tg * 4;
    int tid = threadIdx.x;

    __shared__ float Pm[4][24][28];

    for (int idx = tid; idx < 4 * 576; idx += 512) {
        int dt = idx / 576, r = idx - dt * 576;
        int n = r / 24, m = r - n * 24;
        int t = t0 + dt;
        int j = n / 3, k = n - j * 3;
        int jp = m / 3, kp = m - jp * 3;
        int t1 = t - 7 + j, t2 = t - 7 + jp;
        float v = 0.f;
        if (t1 >= 0 && t2 >= 0)
            v = D[((((b * 3 + k) * 3 + kp) * 128 + t1) << 7) + t2];
        Pm[dt][n][m] = v;
    }
    __syncthreads();

    if (tid < 96) {
        int dt = tid / 24, n = tid - dt * 24;
        float mx = -1e30f;
#pragma unroll
        for (int m = 0; m < 24; ++m) mx = fmaxf(mx, Pm[dt][n][m]);
        float e[24], sum = 0.f;
#pragma unroll
        for (int m = 0; m < 24; ++m) { e[m] = __expf(Pm[dt][n][m] - mx); sum += e[m]; }
        float inv = 1.0f / sum;
#pragma unroll
        for (int m = 0; m < 24; ++m) Pm[dt][n][m] = e[m] * inv;
    }
    __syncthreads();

    int o = tid;
    float wg[33], xw[33];
#pragma unroll
    for (int s = 0; s < 11; ++s) {
        int tp = t0 - 7 + s;
#pragma unroll
        for (int k = 0; k < 3; ++k) {
            int base = (((b * 128 + tp) * 3 + k) << 9) + o;
            bool ok = (tp >= 0);
            wg[s * 3 + k] = ok ? Wg[base] : 0.f;
            xw[s * 3 + k] = ok ? Xf[base] : 0.f;
        }
    }
    float wb = W_b[o];
#pragma unroll
    for (int dt = 0; dt < 4; ++dt) {
        float pooled = -1e30f;
#pragma unroll
        for (int n = 0; n < 24; ++n) {
            float s0 = 0.f, s1 = 0.f, s2 = 0.f, s3 = 0.f;
#pragma unroll
            for (int mq = 0; mq < 6; ++mq) {
                float4 p4 = *(const float4*)&Pm[dt][n][mq * 4];
                s0 += p4.x * wg[mq * 4 + 0 + dt * 3];
                s1 += p4.y * wg[mq * 4 + 1 + dt * 3];
                s2 += p4.z * wg[mq * 4 + 2 + dt * 3];
                s3 += p4.w * wg[mq * 4 + 3 + dt * 3];
            }
            float s = ((s0 + s1) + (s2 + s3)) + wb + xw[n + dt * 3];
            pooled = fmaxf(pooled, s);
        }
        int t = t0 + dt;
        int oidx = ((t * 16 + b) << 9) + o;
        unsigned short h = f2bf(pooled), l = f2bf(pooled - bf2f(h));
        Plh[oidx] = h;
        Pll[oidx] = l;
    }
}

// ---------------------------------------------------------------------------
// out[r] = lrelu( sum_c H[r][c]*p3w[c] + p3b )   one wave per row
// ---------------------------------------------------------------------------
__global__ __launch_bounds__(256) void k_final(const float* __restrict__ H,
                                               const float* __restrict__ p3w,
                                               const float* __restrict__ p3b,
                                               float* __restrict__ out) {
    int r = blockIdx.x * 4 + (threadIdx.x >> 6);
    int lane = threadIdx.x & 63;
    const float4* h4 = (const float4*)&H[r << 9];
    const float4* w4 = (const float4*)p3w;
    float4 a1 = h4[lane], a2 = h4[lane + 64];
    float4 b1 = w4[lane], b2 = w4[lane + 64];
    float s = a1.x * b1.x + a1.y * b1.y + a1.z * b1.z + a1.w * b1.w +
              a2.x * b2.x + a2.y * b2.y + a2.z * b2.z + a2.w * b2.w;
#pragma unroll
    for (int off = 32; off; off >>= 1) s += __shfl_down(s, off, 64);
    if (lane == 0) out[r] = lrelu(s + p3b[0]);
}

extern "C" void kernel_launch(void* const* d_in, const int* in_sizes, int n_in,
                              void* d_out, int out_size, void* d_ws, size_t ws_size,
                              hipStream_t stream) {
    const float* out1 = (const float*)d_in[0];
    const float* out2 = (const float*)d_in[1];
    const float* out3 = (const float*)d_in[2];
    const float* theta_w = (const float*)d_in[3];
    const float* phi_w = (const float*)d_in[4];
    const float* g_w = (const float*)d_in[5];
    const float* W_w = (const float*)d_in[6];
    const float* W_b = (const float*)d_in[7];
    const float* p1_w = (const float*)d_in[8];
    const float* p2_w = (const float*)d_in[9];
    const float* p3_w = (const float*)d_in[10];
    const float* p3_b = (const float*)d_in[11];
    float* outp = (float*)d_out;

    // ---- workspace layout (bytes) ----
    char* wsb = (char*)d_ws;
    unsigned short* Whi = (unsigned short*)(wsb + 0);         // 1024x512 bf16 (Mw | Wg_w)
    unsigned short* Wlo = (unsigned short*)(wsb + 1048576);
    unsigned short* p1h = (unsigned short*)(wsb + 2097152);
    unsigned short* p1l = (unsigned short*)(wsb + 2621440);
    unsigned short* p2h = (unsigned short*)(wsb + 3145728);
    unsigned short* p2l = (unsigned short*)(wsb + 3670016);
    unsigned short* WwH = (unsigned short*)(wsb + 4194304);
    unsigned short* WwL = (unsigned short*)(wsb + 4718592);
    unsigned short* TtH = (unsigned short*)(wsb + 5242880);
    unsigned short* TtL = (unsigned short*)(wsb + 5767168);
    unsigned short* PtH = (unsigned short*)(wsb + 6291456);
    unsigned short* PtL = (unsigned short*)(wsb + 6815744);
    unsigned short* GtH = (unsigned short*)(wsb + 7340032);
    unsigned short* GtL = (unsigned short*)(wsb + 7864320);
    unsigned short* Xh  = (unsigned short*)(wsb + 8388608);   // 6144x512 bf16
    unsigned short* Xl  = (unsigned short*)(wsb + 14680064);
    unsigned short* Yh  = (unsigned short*)(wsb + 20971520);  // 6144x512 bf16
    unsigned short* Yl  = (unsigned short*)(wsb + 27262976);
    float* Wg = (float*)(wsb + 33554432);                     // 6144x512 fp32 (wgemm partials pre-k_ga)
    float* D  = (float*)(wsb + 46137344);                     // 144x128x128 fp32 (MLP partials post-k_mix)
    float* Xf = (float*)(wsb + 55574528);                     // 6144x512 fp32
    // aliases (dead-buffer reuse):
    float* Pw = Wg;
    float* Pp = D;
    unsigned short* Plh = (unsigned short*)(wsb + 20971520);  // over Yh (dead after gram)
    unsigned short* Pll = (unsigned short*)(wsb + 23068672);
    unsigned short* h1h = (unsigned short*)(wsb + 27262976);  // over Yl (dead after gram)
    unsigned short* h1l = (unsigned short*)(wsb + 29360128);
    float* h2 = (float*)(wsb + 8388608);                      // over Xh (dead after mix)

    // 1. all splits fused (weights + inputs)
    k_split_all<<<dim3(4608), dim3(32, 8), 0, stream>>>(
        theta_w, phi_w, g_w, W_w, p1_w, p2_w, out1, out2, out3,
        TtH, TtL, PtH, PtL, GtH, GtL, WwH, WwL, p1h, p1l, p2h, p2l,
        Xh, Xl, Xf);
    // 2. weight GEMMs split-K=4 -> reduce+split into Whi/Wlo
    k_wgemm_sk<<<dim3(4, 4, 8), 256, 0, stream>>>(WwH, WwL, GtH, GtL, TtH, TtL,
                                                  PtH, PtL, Pw);
    k_red<4, 0><<<dim3(512), 256, 0, stream>>>(Pw, 524288, Whi, Wlo, nullptr);
    // 3. stage A: Y (bf16 hi/lo) + Wg (fp32)
    k_ga<<<dim3(48, 8), 256, 0, stream>>>(Whi, Wlo, Xh, Xl, Yh, Yl, Wg);
    // 4. band gram matrices
    k_gram3<<<dim3(1152), 64, 0, stream>>>(Xh, Xl, Yh, Yl, D);
    // 5. softmax + mix + residual + pool (4 t's per block)
    k_mix<<<dim3(512), 512, 0, stream>>>(Xf, Wg, D, W_b, Plh, Pll);
    // 6. MLP1 split-K=2 -> reduce+lrelu+split
    k_mlp_sk<<<dim3(16, 4, 2), 256, 0, stream>>>(Plh, Pll, p1h, p1l, Pp);
    k_red<2, 1><<<dim3(1024), 256, 0, stream>>>(Pp, 1048576, h1h, h1l, nullptr);
    // 7. MLP2 split-K=2 -> reduce+lrelu -> h2 fp32
    k_mlp_sk<<<dim3(16, 4, 2), 256, 0, stream>>>(h1h, h1l, p2h, p2l, Pp);
    k_red<2, 2><<<dim3(1024), 256, 0, stream>>>(Pp, 1048576, nullptr, nullptr, h2);
    // 8. final projection
    k_final<<<dim3(512), 256, 0, stream>>>(h2, p3_w, p3_b, outp);
}

// Round 18
// 116.606 us; speedup vs baseline: 1.0918x; 1.0219x over previous
//
#include <hip/hip_runtime.h>

typedef __attribute__((ext_vector_type(8))) short short8;
typedef __attribute__((ext_vector_type(4))) float float4v;
typedef __attribute__((ext_vector_type(4))) unsigned int uint4v;
typedef __attribute__((ext_vector_type(4))) unsigned short ushort4v;

__device__ __forceinline__ float lrelu(float v) { return v >= 0.f ? v : 0.01f * v; }

__device__ __forceinline__ unsigned short f2bf(float x) {
    union { float f; unsigned u; } c; c.f = x;
    unsigned r = (c.u + 0x7FFFu + ((c.u >> 16) & 1u)) >> 16;
    return (unsigned short)r;
}
__device__ __forceinline__ float bf2f(unsigned short h) {
    union { unsigned u; float f; } c; c.u = ((unsigned)h) << 16;
    return c.f;
}

// async global->LDS, 16B per lane. LDS dest must be wave-uniform base
// (HW adds lane*16); global src is per-lane (pre-swizzled).
__device__ __forceinline__ void gload16(const unsigned short* g, unsigned short* l) {
    __builtin_amdgcn_global_load_lds(
        (const __attribute__((address_space(1))) unsigned int*)g,
        (__attribute__((address_space(3))) unsigned int*)l, 16, 0, 0);
}

// ===========================================================================
// Shared MFMA core (K-range for split-K): C[128x128] += A.B^T over
// K in [kBeg,kEnd), split-bf16 (hh+hl+lh ~ fp32). 256 threads, 4 waves 2x2.
// LDS: 4 tiles [128][64]. gload_lds direct staging, both-sides XOR swizzle.
// ===========================================================================
__device__ __forceinline__ void mfma_core(
    const unsigned short* __restrict__ Ah, const unsigned short* __restrict__ Al, int lda,
    const unsigned short* __restrict__ Bh, const unsigned short* __restrict__ Bl, int ldb,
    unsigned short* lds, float4v acc[4][4], int kBeg, int kEnd) {
    const int tid = threadIdx.x;
    const int lane = tid & 63, wave = tid >> 6;
    const int wm = wave >> 1, wn = wave & 1;
    const int l15 = lane & 15, lhi = lane >> 4;
    unsigned short* LAh = lds;
    unsigned short* LAl = lds + 8192;
    unsigned short* LBh = lds + 16384;
    unsigned short* LBl = lds + 24576;

    for (int k0 = kBeg; k0 < kEnd; k0 += 64) {
#pragma unroll
        for (int tile = 0; tile < 4; ++tile) {
            const unsigned short* s = (tile == 0) ? Ah : (tile == 1) ? Al : (tile == 2) ? Bh : Bl;
            int ld = (tile < 2) ? lda : ldb;
            unsigned short* dbase = lds + tile * 8192;
#pragma unroll
            for (int it = 0; it < 4; ++it) {
                int idx = it * 256 + tid;
                int row = idx >> 3, ch = idx & 7;
                gload16(&s[row * ld + k0 + ((ch ^ (row & 7)) << 3)],
                        dbase + ((it * 256 + wave * 64) << 3));
            }
        }
        __syncthreads();
#pragma unroll
        for (int ks = 0; ks < 2; ++ks) {
            short8 ah[4], al[4], bh[4], bl[4];
#pragma unroll
            for (int m = 0; m < 4; ++m) {
                int r = wm * 64 + m * 16 + l15;
                int off = r * 64 + (((ks * 4 + lhi) ^ (r & 7)) * 8);
                ah[m] = *(const short8*)&LAh[off];
                al[m] = *(const short8*)&LAl[off];
            }
#pragma unroll
            for (int n = 0; n < 4; ++n) {
                int r = wn * 64 + n * 16 + l15;
                int off = r * 64 + (((ks * 4 + lhi) ^ (r & 7)) * 8);
                bh[n] = *(const short8*)&LBh[off];
                bl[n] = *(const short8*)&LBl[off];
            }
#pragma unroll
            for (int m = 0; m < 4; ++m)
#pragma unroll
                for (int n = 0; n < 4; ++n) {
                    acc[m][n] = __builtin_amdgcn_mfma_f32_16x16x32_bf16(ah[m], bh[n], acc[m][n], 0, 0, 0);
                    acc[m][n] = __builtin_amdgcn_mfma_f32_16x16x32_bf16(ah[m], bl[n], acc[m][n], 0, 0, 0);
                    acc[m][n] = __builtin_amdgcn_mfma_f32_16x16x32_bf16(al[m], bh[n], acc[m][n], 0, 0, 0);
                }
        }
        __syncthreads();
    }
}

// ---------------------------------------------------------------------------
// Fused ALL splits: flat grid 4608, block (32,8).
//   bz < 1536: weight splits (0-2 transpose theta/phi/g; 3-5 straight).
//   bz >= 1536: input transpose+split (Xh/Xl/Xf).
// ---------------------------------------------------------------------------
__global__ __launch_bounds__(256) void k_split_all(
    const float* __restrict__ tw, const float* __restrict__ fw,
    const float* __restrict__ gw, const float* __restrict__ ww,
    const float* __restrict__ p1w, const float* __restrict__ p2w,
    const float* __restrict__ o1, const float* __restrict__ o2,
    const float* __restrict__ o3,
    unsigned short* __restrict__ TtH, unsigned short* __restrict__ TtL,
    unsigned short* __restrict__ PtH, unsigned short* __restrict__ PtL,
    unsigned short* __restrict__ GtH, unsigned short* __restrict__ GtL,
    unsigned short* __restrict__ WwH, unsigned short* __restrict__ WwL,
    unsigned short* __restrict__ p1h, unsigned short* __restrict__ p1l,
    unsigned short* __restrict__ p2h, unsigned short* __restrict__ p2l,
    unsigned short* __restrict__ Xh, unsigned short* __restrict__ Xl,
    float* __restrict__ Xf) {
    int bz = blockIdx.x;
    int tx = threadIdx.x, ty = threadIdx.y;
    __shared__ float tile[32][33];
    if (bz < 1536) {
        int z = bz >> 8, rem = bz & 255;
        int by = rem >> 4, bx = rem & 15;
        int i0 = bx * 32, k0 = by * 32;
        if (z < 3) {
            const float* src = (z == 0) ? tw : (z == 1) ? fw : gw;
            unsigned short* dh = (z == 0) ? TtH : (z == 1) ? PtH : GtH;
            unsigned short* dl = (z == 0) ? TtL : (z == 1) ? PtL : GtL;
#pragma unroll
            for (int i = 0; i < 4; ++i)
                tile[ty + i * 8][tx] = src[(k0 + ty + i * 8) * 512 + i0 + tx];
            __syncthreads();
#pragma unroll
            for (int i = 0; i < 4; ++i) {
                int row = i0 + ty + i * 8;
                float v = tile[tx][ty + i * 8];
                unsigned short h = f2bf(v), l = f2bf(v - bf2f(h));
                int idx = row * 512 + k0 + tx;
                dh[idx] = h;
                dl[idx] = l;
            }
        } else {
            const float* src = (z == 3) ? ww : (z == 4) ? p1w : p2w;
            unsigned short* dh = (z == 3) ? WwH : (z == 4) ? p1h : p2h;
            unsigned short* dl = (z == 3) ? WwL : (z == 4) ? p1l : p2l;
#pragma unroll
            for (int i = 0; i < 4; ++i) {
                int r = k0 + ty + i * 8;
                int idx = r * 512 + i0 + tx;
                float v = src[idx];
                unsigned short h = f2bf(v), l = f2bf(v - bf2f(h));
                dh[idx] = h;
                dl[idx] = l;
            }
        }
    } else {
        int r = bz - 1536;
        int z = r >> 6, rem = r & 63;
        int by = rem >> 4, bx = rem & 15;
        int b = z / 3, k = z - b * 3;
        const float* In = (k == 0) ? o1 : ((k == 1) ? o2 : o3);
        int c0 = bx * 32, t0 = by * 32;
#pragma unroll
        for (int i = 0; i < 4; ++i)
            tile[ty + i * 8][tx] = In[(b * 512 + c0 + ty + i * 8) * 128 + t0 + tx];
        __syncthreads();
#pragma unroll
        for (int i = 0; i < 4; ++i) {
            int t = t0 + ty + i * 8;
            float v = tile[tx][ty + i * 8];
            unsigned short h = f2bf(v), l = f2bf(v - bf2f(h));
            int idx = ((b * 128 + t) * 3 + k) * 512 + c0 + tx;
            Xh[idx] = h;
            Xl[idx] = l;
            Xf[idx] = v;
        }
    }
}

// ---------------------------------------------------------------------------
// Weight GEMMs, split-K=4: grid (4,4,8): z = wg*4 + kslice.
// ---------------------------------------------------------------------------
__global__ __launch_bounds__(256) void k_wgemm_sk(
    const unsigned short* __restrict__ WwH, const unsigned short* __restrict__ WwL,
    const unsigned short* __restrict__ GtH, const unsigned short* __restrict__ GtL,
    const unsigned short* __restrict__ TtH, const unsigned short* __restrict__ TtL,
    const unsigned short* __restrict__ PtH, const unsigned short* __restrict__ PtL,
    float* __restrict__ Pw) {
    __shared__ unsigned short lds[32768];
    int i0 = blockIdx.y * 128, j0 = blockIdx.x * 128;
    int wg = blockIdx.z >> 2, kslice = blockIdx.z & 3;
    const unsigned short* Ah = (wg == 0 ? WwH : TtH) + i0 * 512;
    const unsigned short* Al = (wg == 0 ? WwL : TtL) + i0 * 512;
    const unsigned short* Bh = (wg == 0 ? GtH : PtH) + j0 * 512;
    const unsigned short* Bl = (wg == 0 ? GtL : PtL) + j0 * 512;
    float4v acc[4][4];
#pragma unroll
    for (int m = 0; m < 4; ++m)
#pragma unroll
        for (int n = 0; n < 4; ++n) acc[m][n] = (float4v){0.f, 0.f, 0.f, 0.f};

    mfma_core(Ah, Al, 512, Bh, Bl, 512, lds, acc, kslice * 128, kslice * 128 + 128);

    int lane = threadIdx.x & 63, wave = threadIdx.x >> 6;
    int wm = wave >> 1, wn = wave & 1, l15 = lane & 15, lhi = lane >> 4;
    int rowbase = (wg == 0) ? 512 + i0 : i0;
    float* P = Pw + kslice * 524288;
#pragma unroll
    for (int m = 0; m < 4; ++m)
#pragma unroll
        for (int n = 0; n < 4; ++n) {
            int bcol = j0 + wn * 64 + n * 16 + l15;
#pragma unroll
            for (int i = 0; i < 4; ++i) {
                int r = rowbase + wm * 64 + m * 16 + lhi * 4 + i;
                P[r * 512 + bcol] = acc[m][n][i];
            }
        }
}

// ---------------------------------------------------------------------------
// Partial reduce: MODE 0 split, 1 lrelu+split.
// ---------------------------------------------------------------------------
template <int NPART, int MODE>
__global__ __launch_bounds__(256) void k_red(
    const float* __restrict__ P, int stride,
    unsigned short* __restrict__ Ch, unsigned short* __restrict__ Cl) {
    int i4 = blockIdx.x * 256 + threadIdx.x;
    float4v v = ((const float4v*)P)[i4];
#pragma unroll
    for (int p = 1; p < NPART; ++p) {
        float4v u = ((const float4v*)(P + (size_t)p * stride))[i4];
#pragma unroll
        for (int j = 0; j < 4; ++j) v[j] += u[j];
    }
    if (MODE >= 1) {
#pragma unroll
        for (int j = 0; j < 4; ++j) v[j] = lrelu(v[j]);
    }
    ushort4v h, l;
#pragma unroll
    for (int j = 0; j < 4; ++j) {
        h[j] = f2bf(v[j]);
        l[j] = f2bf(v[j] - bf2f(h[j]));
    }
    ((ushort4v*)Ch)[i4] = h;
    ((ushort4v*)Cl)[i4] = l;
}

// ---------------------------------------------------------------------------
// Stage A via MFMA: grid (48, 8): x = b*3+kin, y = o-tile
// ---------------------------------------------------------------------------
__global__ __launch_bounds__(256) void k_ga(
    const unsigned short* __restrict__ Whi, const unsigned short* __restrict__ Wlo,
    const unsigned short* __restrict__ Xh, const unsigned short* __restrict__ Xl,
    unsigned short* __restrict__ Yh, unsigned short* __restrict__ Yl,
    float* __restrict__ Wg) {
    __shared__ unsigned short lds[32768];
    int bk = blockIdx.x, y = blockIdx.y;
    int b = bk / 3, kin = bk - b * 3;
    int bbase = (b * 384 + kin) * 512;
    float4v acc[4][4];
#pragma unroll
    for (int m = 0; m < 4; ++m)
#pragma unroll
        for (int n = 0; n < 4; ++n) acc[m][n] = (float4v){0.f, 0.f, 0.f, 0.f};

    mfma_core(Whi + y * 128 * 512, Wlo + y * 128 * 512, 512,
              Xh + bbase, Xl + bbase, 1536, lds, acc, 0, 512);

    int lane = threadIdx.x & 63, wave = threadIdx.x >> 6;
    int wm = wave >> 1, wn = wave & 1, l15 = lane & 15, lhi = lane >> 4;
    int wsel = y >> 2, o0 = (y & 3) * 128;
#pragma unroll
    for (int m = 0; m < 4; ++m)
#pragma unroll
        for (int n = 0; n < 4; ++n) {
            int o_in = wm * 64 + m * 16 + lhi * 4;
            int t = wn * 64 + n * 16 + l15;
            int idx = bbase + t * 1536 + o0 + o_in;
            if (wsel == 1) {
                *(float4v*)&Wg[idx] = acc[m][n];
            } else {
                ushort4v h, l;
#pragma unroll
                for (int i = 0; i < 4; ++i) {
                    float v = acc[m][n][i];
                    h[i] = f2bf(v);
                    l[i] = f2bf(v - bf2f(h[i]));
                }
                *(ushort4v*)&Yh[idx] = h;
                *(ushort4v*)&Yl[idx] = l;
            }
        }
}

// ---------------------------------------------------------------------------
// Band gram: |t1-t2|<=7 only. grid 1152 XCD-swizzled, block 64.
// ---------------------------------------------------------------------------
__global__ __launch_bounds__(64) void k_gram3(
    const unsigned short* __restrict__ Xh, const unsigned short* __restrict__ Xl,
    const unsigned short* __restrict__ Yh, const unsigned short* __restrict__ Yl,
    float* __restrict__ D) {
    __shared__ unsigned short lds[8192];
    int orig = blockIdx.x;
    int idx = (orig & 7) * 144 + (orig >> 3);
    int mat = idx >> 3, c = idx & 7;
    int b = mat / 9, r9 = mat - b * 9, k = r9 / 3, kp = r9 - k * 3;
    const unsigned short* Ahg = Xh + (b * 384 + k) * 512;
    const unsigned short* Alg = Xl + (b * 384 + k) * 512;
    const unsigned short* Bhg = Yh + (b * 384 + kp) * 512;
    const unsigned short* Blg = Yl + (b * 384 + kp) * 512;
    int t1b = c * 16, t2b0 = c * 16 - 16;
    unsigned short* LAh = lds;
    unsigned short* LAl = lds + 1024;
    unsigned short* LBh = lds + 2048;
    unsigned short* LBl = lds + 5120;
    int tid = threadIdx.x;
    int l15 = tid & 15, lhi = tid >> 4;
    float4v acc[3];
    acc[0] = (float4v){0.f, 0.f, 0.f, 0.f};
    acc[1] = (float4v){0.f, 0.f, 0.f, 0.f};
    acc[2] = (float4v){0.f, 0.f, 0.f, 0.f};

    for (int k0 = 0; k0 < 512; k0 += 64) {
#pragma unroll
        for (int it = 0; it < 2; ++it) {
            int i2 = it * 64 + tid;
            int row = i2 >> 3, ch = i2 & 7;
            int g = (t1b + row) * 1536 + k0 + ((ch ^ (row & 7)) << 3);
            gload16(&Ahg[g], LAh + ((it * 64) << 3));
            gload16(&Alg[g], LAl + ((it * 64) << 3));
        }
#pragma unroll
        for (int it = 0; it < 6; ++it) {
            int i2 = it * 64 + tid;
            int row = i2 >> 3, ch = i2 & 7;
            int t2 = t2b0 + row;
            int t2c = t2 < 0 ? 0 : (t2 > 127 ? 127 : t2);
            int g = t2c * 1536 + k0 + ((ch ^ (row & 7)) << 3);
            gload16(&Bhg[g], LBh + ((it * 64) << 3));
            gload16(&Blg[g], LBl + ((it * 64) << 3));
        }
        __syncthreads();
#pragma unroll
        for (int ks = 0; ks < 2; ++ks) {
            int offa = l15 * 64 + (((ks * 4 + lhi) ^ (l15 & 7)) * 8);
            short8 ah = *(const short8*)&LAh[offa];
            short8 al = *(const short8*)&LAl[offa];
#pragma unroll
            for (int tl = 0; tl < 3; ++tl) {
                int rb = tl * 16 + l15;
                int offb = rb * 64 + (((ks * 4 + lhi) ^ (rb & 7)) * 8);
                short8 bh = *(const short8*)&LBh[offb];
                short8 bl = *(const short8*)&LBl[offb];
                acc[tl] = __builtin_amdgcn_mfma_f32_16x16x32_bf16(ah, bh, acc[tl], 0, 0, 0);
                acc[tl] = __builtin_amdgcn_mfma_f32_16x16x32_bf16(ah, bl, acc[tl], 0, 0, 0);
                acc[tl] = __builtin_amdgcn_mfma_f32_16x16x32_bf16(al, bh, acc[tl], 0, 0, 0);
            }
        }
        __syncthreads();
    }
    float* Dm = D + mat * 16384;
#pragma unroll
    for (int tl = 0; tl < 3; ++tl) {
        int t2base = t2b0 + tl * 16;
        if (t2base < 0 || t2base > 127) continue;
        int t2 = t2base + l15;
#pragma unroll
        for (int i = 0; i < 4; ++i) {
            int t1 = t1b + lhi * 4 + i;
            Dm[t1 * 128 + t2] = acc[tl][i];
        }
    }
}

// ---------------------------------------------------------------------------
// MLP layer, split-K=2: grid (16,4,2). Partials; activation in reducer.
// ---------------------------------------------------------------------------
__global__ __launch_bounds__(256) void k_mlp_sk(
    const unsigned short* __restrict__ Ahi, const unsigned short* __restrict__ Alo,
    const unsigned short* __restrict__ Bhi, const unsigned short* __restrict__ Blo,
    float* __restrict__ Pp) {
    __shared__ unsigned short lds[32768];
    int r0 = blockIdx.x * 128, o0 = blockIdx.y * 128;
    int kslice = blockIdx.z;
    float4v acc[4][4];
#pragma unroll
    for (int m = 0; m < 4; ++m)
#pragma unroll
        for (int n = 0; n < 4; ++n) acc[m][n] = (float4v){0.f, 0.f, 0.f, 0.f};

    mfma_core(Ahi + r0 * 512, Alo + r0 * 512, 512, Bhi + o0 * 512, Blo + o0 * 512, 512,
              lds, acc, kslice * 256, kslice * 256 + 256);

    int lane = threadIdx.x & 63, wave = threadIdx.x >> 6;
    int wm = wave >> 1, wn = wave & 1, l15 = lane & 15, lhi = lane >> 4;
    float* P = Pp + (size_t)kslice * 1048576;
#pragma unroll
    for (int m = 0; m < 4; ++m)
#pragma unroll
        for (int n = 0; n < 4; ++n) {
            int o = o0 + wn * 64 + n * 16 + l15;
#pragma unroll
            for (int i = 0; i < 4; ++i) {
                int r = r0 + wm * 64 + m * 16 + lhi * 4 + i;
                P[r * 512 + o] = acc[m][n][i];
            }
        }
}

// ---------------------------------------------------------------------------
// Mix, 4 t's per block (proven body): gather band f, softmax (96-way),
// union preload 11 slots x 3, float4 Pm. grid 512 XCD-swizzled, block 512.
// ---------------------------------------------------------------------------
__global__ __launch_bounds__(512) void k_mix(
    const float* __restrict__ Xf, const float* __restrict__ Wg,
    const float* __restrict__ D, const float* __restrict__ W_b,
    unsigned short* __restrict__ Plh, unsigned short* __restrict__ Pll) {
    int orig = blockIdx.x;
    int bid = ((orig & 7) << 6) | (orig >> 3);  // 512 = 8 * 64, bijective
    int b = bid >> 5, tg = bid & 31;
    int t0 = tg * 4;
    int tid = threadIdx.x;

    __shared__ float Pm[4][24][28];

    for (int idx = tid; idx < 4 * 576; idx += 512) {
        int dt = idx / 576, r = idx - dt * 576;
        int n = r / 24, m = r - n * 24;
        int t = t0 + dt;
        int j = n / 3, k = n - j * 3;
        int jp = m / 3, kp = m - jp * 3;
        int t1 = t - 7 + j, t2 = t - 7 + jp;
        float v = 0.f;
        if (t1 >= 0 && t2 >= 0)
            v = D[((((b * 3 + k) * 3 + kp) * 128 + t1) << 7) + t2];
        Pm[dt][n][m] = v;
    }
    __syncthreads();

    if (tid < 96) {
        int dt = tid / 24, n = tid - dt * 24;
        float mx = -1e30f;
#pragma unroll
        for (int m = 0; m < 24; ++m) mx = fmaxf(mx, Pm[dt][n][m]);
        float e[24], sum = 0.f;
#pragma unroll
        for (int m = 0; m < 24; ++m) { e[m] = __expf(Pm[dt][n][m] - mx); sum += e[m]; }
        float inv = 1.0f / sum;
#pragma unroll
        for (int m = 0; m < 24; ++m) Pm[dt][n][m] = e[m] * inv;
    }
    __syncthreads();

    int o = tid;
    float wg[33], xw[33];
#pragma unroll
    for (int s = 0; s < 11; ++s) {
        int tp = t0 - 7 + s;
#pragma unroll
        for (int k = 0; k < 3; ++k) {
            int base = (((b * 128 + tp) * 3 + k) << 9) + o;
            bool ok = (tp >= 0);
            wg[s * 3 + k] = ok ? Wg[base] : 0.f;
            xw[s * 3 + k] = ok ? Xf[base] : 0.f;
        }
    }
    float wb = W_b[o];
#pragma unroll
    for (int dt = 0; dt < 4; ++dt) {
        float pooled = -1e30f;
#pragma unroll
        for (int n = 0; n < 24; ++n) {
            float s0 = 0.f, s1 = 0.f, s2 = 0.f, s3 = 0.f;
#pragma unroll
            for (int mq = 0; mq < 6; ++mq) {
                float4 p4 = *(const float4*)&Pm[dt][n][mq * 4];
                s0 += p4.x * wg[mq * 4 + 0 + dt * 3];
                s1 += p4.y * wg[mq * 4 + 1 + dt * 3];
                s2 += p4.z * wg[mq * 4 + 2 + dt * 3];
                s3 += p4.w * wg[mq * 4 + 3 + dt * 3];
            }
            float s = ((s0 + s1) + (s2 + s3)) + wb + xw[n + dt * 3];
            pooled = fmaxf(pooled, s);
        }
        int t = t0 + dt;
        int oidx = ((t * 16 + b) << 9) + o;
        unsigned short h = f2bf(pooled), l = f2bf(pooled - bf2f(h));
        Plh[oidx] = h;
        Pll[oidx] = l;
    }
}

// ---------------------------------------------------------------------------
// Fused MLP2-reduce + final projection (r18): for each row r,
// h2[c] = lrelu(P0[r][c] + P1[r][c]); out[r] = lrelu(sum_c h2[c]*p3w[c] + p3b).
// Same summation/order as old k_red<2,2> + k_final -> bit-identical.
// grid 512 blocks of 256 (one wave per row).
// ---------------------------------------------------------------------------
__global__ __launch_bounds__(256) void k_redfinal(
    const float* __restrict__ P, const float* __restrict__ p3w,
    const float* __restrict__ p3b, float* __restrict__ out) {
    int r = blockIdx.x * 4 + (threadIdx.x >> 6);
    int lane = threadIdx.x & 63;
    const float* P0 = P + (size_t)r * 512;
    const float* P1 = P0 + 1048576;
    float4 a1 = *(const float4*)&P0[lane * 4];
    float4 c1 = *(const float4*)&P1[lane * 4];
    float4 a2 = *(const float4*)&P0[256 + lane * 4];
    float4 c2 = *(const float4*)&P1[256 + lane * 4];
    a1.x = lrelu(a1.x + c1.x); a1.y = lrelu(a1.y + c1.y);
    a1.z = lrelu(a1.z + c1.z); a1.w = lrelu(a1.w + c1.w);
    a2.x = lrelu(a2.x + c2.x); a2.y = lrelu(a2.y + c2.y);
    a2.z = lrelu(a2.z + c2.z); a2.w = lrelu(a2.w + c2.w);
    const float4* w4 = (const float4*)p3w;
    float4 b1 = w4[lane], b2 = w4[lane + 64];
    float s = a1.x * b1.x + a1.y * b1.y + a1.z * b1.z + a1.w * b1.w +
              a2.x * b2.x + a2.y * b2.y + a2.z * b2.z + a2.w * b2.w;
#pragma unroll
    for (int off = 32; off; off >>= 1) s += __shfl_down(s, off, 64);
    if (lane == 0) out[r] = lrelu(s + p3b[0]);
}

extern "C" void kernel_launch(void* const* d_in, const int* in_sizes, int n_in,
                              void* d_out, int out_size, void* d_ws, size_t ws_size,
                              hipStream_t stream) {
    const float* out1 = (const float*)d_in[0];
    const float* out2 = (const float*)d_in[1];
    const float* out3 = (const float*)d_in[2];
    const float* theta_w = (const float*)d_in[3];
    const float* phi_w = (const float*)d_in[4];
    const float* g_w = (const float*)d_in[5];
    const float* W_w = (const float*)d_in[6];
    const float* W_b = (const float*)d_in[7];
    const float* p1_w = (const float*)d_in[8];
    const float* p2_w = (const float*)d_in[9];
    const float* p3_w = (const float*)d_in[10];
    const float* p3_b = (const float*)d_in[11];
    float* outp = (float*)d_out;

    // ---- workspace layout (bytes) ----
    char* wsb = (char*)d_ws;
    unsigned short* Whi = (unsigned short*)(wsb + 0);         // 1024x512 bf16 (Mw | Wg_w)
    unsigned short* Wlo = (unsigned short*)(wsb + 1048576);
    unsigned short* p1h = (unsigned short*)(wsb + 2097152);
    unsigned short* p1l = (unsigned short*)(wsb + 2621440);
    unsigned short* p2h = (unsigned short*)(wsb + 3145728);
    unsigned short* p2l = (unsigned short*)(wsb + 3670016);
    unsigned short* WwH = (unsigned short*)(wsb + 4194304);
    unsigned short* WwL = (unsigned short*)(wsb + 4718592);
    unsigned short* TtH = (unsigned short*)(wsb + 5242880);
    unsigned short* TtL = (unsigned short*)(wsb + 5767168);
    unsigned short* PtH = (unsigned short*)(wsb + 6291456);
    unsigned short* PtL = (unsigned short*)(wsb + 6815744);
    unsigned short* GtH = (unsigned short*)(wsb + 7340032);
    unsigned short* GtL = (unsigned short*)(wsb + 7864320);
    unsigned short* Xh  = (unsigned short*)(wsb + 8388608);   // 6144x512 bf16
    unsigned short* Xl  = (unsigned short*)(wsb + 14680064);
    unsigned short* Yh  = (unsigned short*)(wsb + 20971520);  // 6144x512 bf16
    unsigned short* Yl  = (unsigned short*)(wsb + 27262976);
    float* Wg = (float*)(wsb + 33554432);                     // 6144x512 fp32 (wgemm partials pre-k_ga)
    float* D  = (float*)(wsb + 46137344);                     // 144x128x128 fp32 (MLP partials post-k_mix)
    float* Xf = (float*)(wsb + 55574528);                     // 6144x512 fp32
    // aliases (dead-buffer reuse):
    float* Pw = Wg;
    float* Pp = D;
    unsigned short* Plh = (unsigned short*)(wsb + 20971520);  // over Yh (dead after gram)
    unsigned short* Pll = (unsigned short*)(wsb + 23068672);
    unsigned short* h1h = (unsigned short*)(wsb + 27262976);  // over Yl (dead after gram)
    unsigned short* h1l = (unsigned short*)(wsb + 29360128);

    // 1. all splits fused (weights + inputs)
    k_split_all<<<dim3(4608), dim3(32, 8), 0, stream>>>(
        theta_w, phi_w, g_w, W_w, p1_w, p2_w, out1, out2, out3,
        TtH, TtL, PtH, PtL, GtH, GtL, WwH, WwL, p1h, p1l, p2h, p2l,
        Xh, Xl, Xf);
    // 2. weight GEMMs split-K=4 -> reduce+split into Whi/Wlo
    k_wgemm_sk<<<dim3(4, 4, 8), 256, 0, stream>>>(WwH, WwL, GtH, GtL, TtH, TtL,
                                                  PtH, PtL, Pw);
    k_red<4, 0><<<dim3(512), 256, 0, stream>>>(Pw, 524288, Whi, Wlo);
    // 3. stage A: Y (bf16 hi/lo) + Wg (fp32)
    k_ga<<<dim3(48, 8), 256, 0, stream>>>(Whi, Wlo, Xh, Xl, Yh, Yl, Wg);
    // 4. band gram matrices
    k_gram3<<<dim3(1152), 64, 0, stream>>>(Xh, Xl, Yh, Yl, D);
    // 5. softmax + mix + residual + pool (4 t's per block)
    k_mix<<<dim3(512), 512, 0, stream>>>(Xf, Wg, D, W_b, Plh, Pll);
    // 6. MLP1 split-K=2 -> reduce+lrelu+split
    k_mlp_sk<<<dim3(16, 4, 2), 256, 0, stream>>>(Plh, Pll, p1h, p1l, Pp);
    k_red<2, 1><<<dim3(1024), 256, 0, stream>>>(Pp, 1048576, h1h, h1l);
    // 7. MLP2 split-K=2 -> fused reduce+lrelu+final projection
    k_mlp_sk<<<dim3(16, 4, 2), 256, 0, stream>>>(h1h, h1l, p2h, p2l, Pp);
    k_redfinal<<<dim3(512), 256, 0, stream>>>(Pp, p3_w, p3_b, outp);
}